// Round 1
// baseline (310.924 us; speedup 1.0000x reference)
//
#include <hip/hip_runtime.h>
#include <hip/hip_bf16.h>
#include <hip/hip_cooperative_groups.h>

namespace cg = cooperative_groups;

// MaskedContrastiveLoss: loss = 0.5*[mean_i(rowLSE_i - pos_i) + mean_j(colLSE_j - pos_j)]
// logits = (A @ B^T) * (1/0.07), A,B: [256, 65536] fp32, L2-normalized rows.
//
// Single cooperative kernel: split-K bf16 MFMA GEMM -> grid.sync ->
// partials->logits reduction (coalesced, high-ILP) -> grid.sync ->
// all 512 row/col LSE tasks in parallel -> atomicAdd into out.
// This removes 2 kernel-launch boundaries and the 1-wave/SIMD latency-bound
// reduce_rows of the previous version.

#define D_DIM 65536
#define B_DIM 256
#define LDK 72  // padded LDS row stride (elements) to break bank conflicts

constexpr float TEMP = 1.0f / 0.07f;

typedef short short8 __attribute__((ext_vector_type(8)));
typedef float floatx4 __attribute__((ext_vector_type(4)));

__device__ inline unsigned short f2bf(float f) {
  unsigned u = __builtin_bit_cast(unsigned, f);
  unsigned rounding = 0x7fffu + ((u >> 16) & 1u);  // RNE (inputs are finite/normal)
  return (unsigned short)((u + rounding) >> 16);
}

__device__ inline void st_bf16x4(unsigned short* dst, float4 v) {
  uint2 u;
  u.x = (unsigned)f2bf(v.x) | ((unsigned)f2bf(v.y) << 16);
  u.y = (unsigned)f2bf(v.z) | ((unsigned)f2bf(v.w) << 16);
  *(uint2*)dst = u;
}

// Cooperative: grid = min(4*C, co-resident capacity); phase 1 grid-strides
// over the 4*C (tile, K-chunk) work items.
__global__ __launch_bounds__(256, 2) void fused(
    const float* __restrict__ A, const float* __restrict__ Bm,
    float* __restrict__ partials, float* __restrict__ logits,
    float* __restrict__ out, int Kc, int C) {
  const int bid = blockIdx.x;
  const int nblocks = gridDim.x;
  const int t = threadIdx.x;
  const int lane = t & 63;
  const int w = t >> 6;          // wave 0..3
  const int wm = (w & 1) * 64;   // wave sub-tile origin
  const int wn = (w >> 1) * 64;

  // global staging indexing: 16 threads cover one row's 64 floats (16 x float4)
  const int lr = t >> 4;          // base row 0..15 (+p*16)
  const int lc = (t & 15) * 4;    // col within BK=64

  __shared__ unsigned short As[128][LDK];
  __shared__ unsigned short Bs[128][LDK];

  // ---------------- Phase 1: split-K GEMM -> partials ----------------
  for (int wi = bid; wi < 4 * C; wi += nblocks) {
    const int mt = (wi & 1) * 128;
    const int nt = ((wi >> 1) & 1) * 128;
    const int chunk = wi >> 2;
    const size_t k0 = (size_t)chunk * (size_t)Kc;

    const float* Abase = A + (size_t)(mt + lr) * D_DIM + k0 + lc;
    const float* Bbase = Bm + (size_t)(nt + lr) * D_DIM + k0 + lc;

    floatx4 acc[4][4];
#pragma unroll
    for (int mb = 0; mb < 4; ++mb)
#pragma unroll
      for (int nb = 0; nb < 4; ++nb) acc[mb][nb] = (floatx4)0.f;

    float4 ra[8], rb[8];
    const int nst = Kc >> 6;  // stages of BK=64

    // prefetch stage 0
#pragma unroll
    for (int p = 0; p < 8; ++p) {
      ra[p] = *(const float4*)(Abase + (size_t)p * 16 * D_DIM);
      rb[p] = *(const float4*)(Bbase + (size_t)p * 16 * D_DIM);
    }

    for (int s = 0; s < nst; ++s) {
      // convert + stage into LDS
#pragma unroll
      for (int p = 0; p < 8; ++p) {
        st_bf16x4(&As[lr + p * 16][lc], ra[p]);
        st_bf16x4(&Bs[lr + p * 16][lc], rb[p]);
      }
      __syncthreads();

      // issue next stage's global loads (overlap with MFMA below)
      if (s + 1 < nst) {
        const float* Ap = Abase + (size_t)(s + 1) * 64;
        const float* Bp = Bbase + (size_t)(s + 1) * 64;
#pragma unroll
        for (int p = 0; p < 8; ++p) {
          ra[p] = *(const float4*)(Ap + (size_t)p * 16 * D_DIM);
          rb[p] = *(const float4*)(Bp + (size_t)p * 16 * D_DIM);
        }
      }

      // MFMA over BK=64 (two K-steps of 32)
#pragma unroll
      for (int ks = 0; ks < 64; ks += 32) {
        short8 af[4], bf[4];
        const int ko = ks + (lane >> 4) * 8;
#pragma unroll
        for (int mb = 0; mb < 4; ++mb)
          af[mb] = *(const short8*)&As[wm + mb * 16 + (lane & 15)][ko];
#pragma unroll
        for (int nb = 0; nb < 4; ++nb)
          bf[nb] = *(const short8*)&Bs[wn + nb * 16 + (lane & 15)][ko];
#pragma unroll
        for (int mb = 0; mb < 4; ++mb)
#pragma unroll
          for (int nb = 0; nb < 4; ++nb)
            acc[mb][nb] = __builtin_amdgcn_mfma_f32_16x16x32_bf16(
                af[mb], bf[nb], acc[mb][nb], 0, 0, 0);
      }
      __syncthreads();
    }

    // epilogue: write partial tile. C/D layout: col=lane&15, row=(lane>>4)*4+reg
    float* outp = partials + (size_t)chunk * (B_DIM * B_DIM);
#pragma unroll
    for (int mb = 0; mb < 4; ++mb) {
#pragma unroll
      for (int nb = 0; nb < 4; ++nb) {
        const int gi0 = mt + wm + mb * 16 + ((lane >> 4) * 4);
        const int gj = nt + wn + nb * 16 + (lane & 15);
#pragma unroll
        for (int r = 0; r < 4; ++r)
          outp[(size_t)(gi0 + r) * B_DIM + gj] = acc[mb][nb][r];
      }
    }
  }

  __threadfence();
  cg::this_grid().sync();

  // ---------------- Phase 2: partials -> logits (coalesced, unroll-16) ----
  {
    const int nthr = nblocks * 256;
    for (int g = bid * 256 + t; g < B_DIM * B_DIM; g += nthr) {
      const float* p = partials + g;
      float s = 0.f;
#pragma unroll 16
      for (int c = 0; c < C; ++c) s += p[(size_t)c * (B_DIM * B_DIM)];
      logits[g] = s * TEMP;
    }
  }

  __threadfence();
  cg::this_grid().sync();

  // ---------------- Phase 3: 512 LSE tasks (rows then cols), parallel ----
  __shared__ float wsum[4];
  __shared__ float posv;
  for (int task = bid; task < 2 * B_DIM; task += nblocks) {
    __syncthreads();  // protect wsum/posv reuse across loop iterations
    float lg;
    if (task < B_DIM) {
      const int i = task;
      lg = logits[i * B_DIM + t];  // coalesced row read
      if (t == i) posv = lg;
    } else {
      const int j = task - B_DIM;
      lg = logits[t * B_DIM + j];  // strided col read, 256KB L2-resident
    }
    __syncthreads();
    float e = expf(lg);  // |lg| <= 14.3 by Cauchy-Schwarz: no max-shift needed
#pragma unroll
    for (int off = 32; off > 0; off >>= 1) e += __shfl_down(e, off);
    if ((t & 63) == 0) wsum[t >> 6] = e;
    __syncthreads();
    if (t == 0) {
      const float tot = wsum[0] + wsum[1] + wsum[2] + wsum[3];
      float v = logf(tot) * (0.5f / 256.f);
      if (task < B_DIM) v -= posv * (2.f * 0.5f / 256.f);
      atomicAdd(out, v);
    }
  }
}

extern "C" void kernel_launch(void* const* d_in, const int* in_sizes, int n_in,
                              void* d_out, int out_size, void* d_ws, size_t ws_size,
                              hipStream_t stream) {
  (void)in_sizes; (void)n_in; (void)out_size;
  const float* A = (const float*)d_in[0];
  const float* Bm = (const float*)d_in[1];
  float* out = (float*)d_out;

  // ws layout: [logits: 256*256 f32][partials: C * 256*256 f32]
  const size_t per = (size_t)B_DIM * B_DIM * sizeof(float);  // 256 KB
  int C = 128;
  while (C > 1 && (size_t)(C + 1) * per > ws_size) C >>= 1;
  int Kc = D_DIM / C;

  float* logits = (float*)d_ws;
  float* partials = (float*)d_ws + (size_t)B_DIM * B_DIM;

  // co-resident capacity for the cooperative launch (cached; host-only queries,
  // safe under graph capture)
  static int maxgrid = 0;
  if (maxgrid == 0) {
    int dev = 0, nb = 0, ncu = 0;
    hipGetDevice(&dev);
    hipOccupancyMaxActiveBlocksPerMultiprocessor(&nb, fused, 256, 0);
    hipDeviceGetAttribute(&ncu, hipDeviceAttributeMultiprocessorCount, dev);
    maxgrid = (nb > 0 && ncu > 0) ? nb * ncu : 512;
  }
  int grid = 4 * C;
  if (grid > maxgrid) grid = maxgrid;

  hipMemsetAsync(d_out, 0, sizeof(float), stream);
  void* args[] = {(void*)&A, (void*)&Bm, (void*)&partials, (void*)&logits,
                  (void*)&out, (void*)&Kc, (void*)&C};
  hipLaunchCooperativeKernel(fused, dim3(grid), dim3(256), args, 0, stream);
}

// Round 2
// 163.709 us; speedup vs baseline: 1.8993x; 1.8993x over previous
//
#include <hip/hip_runtime.h>
#include <hip/hip_bf16.h>

// MaskedContrastiveLoss: loss = 0.5*[mean_i(rowLSE_i - pos_i) + mean_j(colLSE_j - pos_j)]
// logits = (A @ B^T) * (1/0.07), A,B: [256, 65536] fp32, L2-normalized rows.
//
// Structure: split-K bf16 MFMA GEMM (verified, unchanged from 172µs baseline)
// -> atomic-free epilogue: finalize_rows (partials->logits + rowLSE, unroll-32
// ILP), finalize_cols (colLSE), finalize_out (1-block sum, writes out directly
// so no memset dispatch). Removes 512 contended same-address atomicAdds.

#define D_DIM 65536
#define B_DIM 256
#define LDK 72  // padded LDS row stride (elements) to break bank conflicts

constexpr float TEMP = 1.0f / 0.07f;

typedef short short8 __attribute__((ext_vector_type(8)));
typedef float floatx4 __attribute__((ext_vector_type(4)));

__device__ inline unsigned short f2bf(float f) {
  unsigned u = __builtin_bit_cast(unsigned, f);
  unsigned rounding = 0x7fffu + ((u >> 16) & 1u);  // RNE (inputs are finite/normal)
  return (unsigned short)((u + rounding) >> 16);
}

__device__ inline void st_bf16x4(unsigned short* dst, float4 v) {
  uint2 u;
  u.x = (unsigned)f2bf(v.x) | ((unsigned)f2bf(v.y) << 16);
  u.y = (unsigned)f2bf(v.z) | ((unsigned)f2bf(v.w) << 16);
  *(uint2*)dst = u;
}

// grid = 4*C blocks; block = 256 threads (4 waves).
// blockIdx.x -> (mt in {0,128}, nt in {0,128}, K-chunk)
__global__ __launch_bounds__(256, 2) void gemm_splitk(
    const float* __restrict__ A, const float* __restrict__ Bm,
    float* __restrict__ partials, int Kc) {
  const int bid = blockIdx.x;
  const int mt = (bid & 1) * 128;
  const int nt = ((bid >> 1) & 1) * 128;
  const int chunk = bid >> 2;
  const size_t k0 = (size_t)chunk * (size_t)Kc;

  __shared__ unsigned short As[128][LDK];
  __shared__ unsigned short Bs[128][LDK];

  const int t = threadIdx.x;
  const int lane = t & 63;
  const int w = t >> 6;          // wave 0..3
  const int wm = (w & 1) * 64;   // wave sub-tile origin
  const int wn = (w >> 1) * 64;

  // global staging indexing: 16 threads cover one row's 64 floats (16 x float4)
  const int lr = t >> 4;          // base row 0..15 (+p*16)
  const int lc = (t & 15) * 4;    // col within BK=64

  const float* Abase = A + (size_t)(mt + lr) * D_DIM + k0 + lc;
  const float* Bbase = Bm + (size_t)(nt + lr) * D_DIM + k0 + lc;

  floatx4 acc[4][4];
#pragma unroll
  for (int mb = 0; mb < 4; ++mb)
#pragma unroll
    for (int nb = 0; nb < 4; ++nb) acc[mb][nb] = (floatx4)0.f;

  float4 ra[8], rb[8];
  const int nst = Kc >> 6;  // stages of BK=64

  // prefetch stage 0
#pragma unroll
  for (int p = 0; p < 8; ++p) {
    ra[p] = *(const float4*)(Abase + (size_t)p * 16 * D_DIM);
    rb[p] = *(const float4*)(Bbase + (size_t)p * 16 * D_DIM);
  }

  for (int s = 0; s < nst; ++s) {
    // convert + stage into LDS
#pragma unroll
    for (int p = 0; p < 8; ++p) {
      st_bf16x4(&As[lr + p * 16][lc], ra[p]);
      st_bf16x4(&Bs[lr + p * 16][lc], rb[p]);
    }
    __syncthreads();

    // issue next stage's global loads (overlap with MFMA below)
    if (s + 1 < nst) {
      const float* Ap = Abase + (size_t)(s + 1) * 64;
      const float* Bp = Bbase + (size_t)(s + 1) * 64;
#pragma unroll
      for (int p = 0; p < 8; ++p) {
        ra[p] = *(const float4*)(Ap + (size_t)p * 16 * D_DIM);
        rb[p] = *(const float4*)(Bp + (size_t)p * 16 * D_DIM);
      }
    }

    // MFMA over BK=64 (two K-steps of 32)
#pragma unroll
    for (int ks = 0; ks < 64; ks += 32) {
      short8 af[4], bf[4];
      const int ko = ks + (lane >> 4) * 8;
#pragma unroll
      for (int mb = 0; mb < 4; ++mb)
        af[mb] = *(const short8*)&As[wm + mb * 16 + (lane & 15)][ko];
#pragma unroll
      for (int nb = 0; nb < 4; ++nb)
        bf[nb] = *(const short8*)&Bs[wn + nb * 16 + (lane & 15)][ko];
#pragma unroll
      for (int mb = 0; mb < 4; ++mb)
#pragma unroll
        for (int nb = 0; nb < 4; ++nb)
          acc[mb][nb] = __builtin_amdgcn_mfma_f32_16x16x32_bf16(
              af[mb], bf[nb], acc[mb][nb], 0, 0, 0);
    }
    __syncthreads();
  }

  // epilogue: write partial tile. C/D layout: col=lane&15, row=(lane>>4)*4+reg
  float* outp = partials + (size_t)chunk * (B_DIM * B_DIM);
#pragma unroll
  for (int mb = 0; mb < 4; ++mb) {
#pragma unroll
    for (int nb = 0; nb < 4; ++nb) {
      const int gi0 = mt + wm + mb * 16 + ((lane >> 4) * 4);
      const int gj = nt + wn + nb * 16 + (lane & 15);
#pragma unroll
      for (int r = 0; r < 4; ++r)
        outp[(size_t)(gi0 + r) * B_DIM + gj] = acc[mb][nb][r];
    }
  }
}

// block i: logits row i = TEMP * sum_c partials[c][i][:]; write logits row;
// rowout[i] = rowLSE_i - 2*pos_i. No atomics; unroll-32 gives 4 latency
// batches over the C=128 chain instead of 32.
__global__ void finalize_rows(const float* __restrict__ partials,
                              float* __restrict__ logits,
                              float* __restrict__ rowout, int C) {
  const int i = blockIdx.x;
  const int j = threadIdx.x;
  const float* p = partials + (size_t)i * B_DIM + j;
  float s = 0.f;
#pragma unroll 32
  for (int c = 0; c < C; ++c) s += p[(size_t)c * (B_DIM * B_DIM)];
  const float lg = s * TEMP;
  logits[i * B_DIM + j] = lg;

  __shared__ float posv;
  if (j == i) posv = lg;

  float e = expf(lg);  // |lg| <= 14.3 by Cauchy-Schwarz: no max-shift needed
#pragma unroll
  for (int off = 32; off > 0; off >>= 1) e += __shfl_down(e, off);
  __shared__ float wsum[4];
  if ((j & 63) == 0) wsum[j >> 6] = e;
  __syncthreads();
  if (j == 0) {
    const float tot = wsum[0] + wsum[1] + wsum[2] + wsum[3];
    rowout[i] = logf(tot) - 2.f * posv;
  }
}

// block j: colout[j] = colLSE_j from finalized logits. No atomics.
__global__ void finalize_cols(const float* __restrict__ logits,
                              float* __restrict__ colout) {
  const int j = blockIdx.x;
  const int i = threadIdx.x;
  float e = expf(logits[(size_t)i * B_DIM + j]);
#pragma unroll
  for (int off = 32; off > 0; off >>= 1) e += __shfl_down(e, off);
  __shared__ float wsum[4];
  if ((i & 63) == 0) wsum[i >> 6] = e;
  __syncthreads();
  if (i == 0) {
    const float tot = wsum[0] + wsum[1] + wsum[2] + wsum[3];
    colout[j] = logf(tot);
  }
}

// 1 block: out = (0.5/256) * sum_i(rowout[i] + colout[i]). Writes out
// directly (no memset dispatch needed).
__global__ void finalize_out(const float* __restrict__ rowout,
                             const float* __restrict__ colout,
                             float* __restrict__ out) {
  const int t = threadIdx.x;
  float v = rowout[t] + colout[t];
#pragma unroll
  for (int off = 32; off > 0; off >>= 1) v += __shfl_down(v, off);
  __shared__ float wsum[4];
  if ((t & 63) == 0) wsum[t >> 6] = v;
  __syncthreads();
  if (t == 0) out[0] = (wsum[0] + wsum[1] + wsum[2] + wsum[3]) * (0.5f / 256.f);
}

extern "C" void kernel_launch(void* const* d_in, const int* in_sizes, int n_in,
                              void* d_out, int out_size, void* d_ws, size_t ws_size,
                              hipStream_t stream) {
  (void)in_sizes; (void)n_in; (void)out_size;
  const float* A = (const float*)d_in[0];
  const float* Bm = (const float*)d_in[1];
  float* out = (float*)d_out;

  // ws layout: [logits: 256*256 f32][partials: C * 256*256 f32][rowout 256][colout 256]
  const size_t per = (size_t)B_DIM * B_DIM * sizeof(float);  // 256 KB
  int C = 128;
  while (C > 1 && (size_t)(C + 1) * per + 2 * B_DIM * sizeof(float) > ws_size)
    C >>= 1;
  const int Kc = D_DIM / C;

  float* logits = (float*)d_ws;
  float* partials = (float*)d_ws + (size_t)B_DIM * B_DIM;
  float* rowout = partials + (size_t)C * B_DIM * B_DIM;
  float* colout = rowout + B_DIM;

  gemm_splitk<<<4 * C, 256, 0, stream>>>(A, Bm, partials, Kc);
  finalize_rows<<<B_DIM, B_DIM, 0, stream>>>(partials, logits, rowout, C);
  finalize_cols<<<B_DIM, B_DIM, 0, stream>>>(logits, colout);
  finalize_out<<<1, B_DIM, 0, stream>>>(rowout, colout, out);
}